// Round 5
// baseline (263.066 us; speedup 1.0000x reference)
//
#include <hip/hip_runtime.h>
#include <math.h>

// SecondOrderChannelAttension on MI355X (gfx950)
// B=32, C=64, H=W=96 -> M=9216, RED=8
//
// Main path (3 dispatches):
//   memset  : zero 32 election counters (128 B)
//   K1 fused: per-(batch,chunk) partial Gram via bf16 MFMA + per-wave channel
//             sums, plain coalesced stores. Then threadfence + agent-scope
//             ACQ_REL counter; the LAST block of each batch runs Newton-Schulz
//             + gate MLP reading partials with vectorized cached loads.
//             No spin-waits -> deadlock-free regardless of residency.
//   K2 gate_mul: out = x * gate, one block per (b,c) row.
//
// NOTE: hipLaunchCooperativeKernel is NOT graph-capturable in this harness
// (round 4: dispatch silently dropped). Do not use it.
//
// Fallback (ws too small): proven 3-kernel plain-store path.

#define BB 32
#define CC 64
#define MM 9216
#define NCHUNKS 16

typedef __attribute__((ext_vector_type(8))) short bf16x8;
typedef __attribute__((ext_vector_type(4))) float f32x4;

__device__ __forceinline__ short f2bf(float f) {
  unsigned u = __builtin_bit_cast(unsigned, f);
  return (short)(unsigned short)((u + 0x8000u) >> 16);  // round-half-up, fine here
}
__device__ __forceinline__ float bf2f(short h) {
  unsigned u = ((unsigned)(unsigned short)h) << 16;
  return __builtin_bit_cast(float, u);
}

// ---------------- gram inner loop ----------------
// Fragment trick: for Gram, the B-operand fragment (B[k][n] = X[n][k]) has the
// same lane mapping as the A fragment of X rows -> load once, use twice.
template <int NSTEP>
__device__ __forceinline__ void gram_body(const float* __restrict__ xb, int mwave,
                                          int quad, int col,
                                          f32x4 acc[4][4], float csum[4]) {
  const float* base[4];
#pragma unroll
  for (int rb = 0; rb < 4; rb++)
    base[rb] = xb + (size_t)(rb * 16 + col) * MM + mwave + quad * 8;

  float4 cur[4][2];
#pragma unroll
  for (int rb = 0; rb < 4; rb++) {
    cur[rb][0] = *(const float4*)(base[rb]);
    cur[rb][1] = *(const float4*)(base[rb] + 4);
  }
#pragma unroll
  for (int s = 0; s < NSTEP; s++) {
    float4 nxt[4][2];
    if (s + 1 < NSTEP) {
#pragma unroll
      for (int rb = 0; rb < 4; rb++) {
        const float* p = base[rb] + (s + 1) * 32;
        nxt[rb][0] = *(const float4*)(p);
        nxt[rb][1] = *(const float4*)(p + 4);
      }
    }
    bf16x8 frag[4];
#pragma unroll
    for (int rb = 0; rb < 4; rb++) {
      float v0 = cur[rb][0].x, v1 = cur[rb][0].y, v2 = cur[rb][0].z, v3 = cur[rb][0].w;
      float v4 = cur[rb][1].x, v5 = cur[rb][1].y, v6 = cur[rb][1].z, v7 = cur[rb][1].w;
      csum[rb] += ((v0 + v1) + (v2 + v3)) + ((v4 + v5) + (v6 + v7));
      bf16x8 f;
      f[0] = f2bf(v0); f[1] = f2bf(v1); f[2] = f2bf(v2); f[3] = f2bf(v3);
      f[4] = f2bf(v4); f[5] = f2bf(v5); f[6] = f2bf(v6); f[7] = f2bf(v7);
      frag[rb] = f;
    }
#pragma unroll
    for (int i = 0; i < 4; i++)
#pragma unroll
      for (int j = 0; j < 4; j++)
        acc[i][j] = __builtin_amdgcn_mfma_f32_16x16x32_bf16(frag[i], frag[j],
                                                            acc[i][j], 0, 0, 0);
    if (s + 1 < NSTEP) {
#pragma unroll
      for (int rb = 0; rb < 4; rb++) {
        cur[rb][0] = nxt[rb][0];
        cur[rb][1] = nxt[rb][1];
      }
    }
  }
}

// ---------------- 64x64 NS matmuls (LDS, bf16 MFMA) ----------------
// All NS iterates are symmetric (polynomials in A), so row-major read serves
// as the k-major B fragment.
__device__ __forceinline__ void mm64(short* __restrict__ D, const short* __restrict__ A,
                                     const short* __restrict__ Bm, int tid) {
  int w = tid >> 6, lane = tid & 63, quad = lane >> 4, col = lane & 15;
  f32x4 acc[4];
#pragma unroll
  for (int j = 0; j < 4; j++) acc[j] = (f32x4){0.f, 0.f, 0.f, 0.f};
#pragma unroll
  for (int ks = 0; ks < 2; ks++) {
    int k0 = ks * 32 + quad * 8;
    bf16x8 fa = *(const bf16x8*)(A + (w * 16 + col) * 64 + k0);
#pragma unroll
    for (int j = 0; j < 4; j++) {
      bf16x8 fb = *(const bf16x8*)(Bm + (j * 16 + col) * 64 + k0);
      acc[j] = __builtin_amdgcn_mfma_f32_16x16x32_bf16(fa, fb, acc[j], 0, 0, 0);
    }
  }
#pragma unroll
  for (int j = 0; j < 4; j++)
#pragma unroll
    for (int r = 0; r < 4; r++)
      D[(w * 16 + quad * 4 + r) * 64 + j * 16 + col] = f2bf(acc[j][r]);
}

__device__ __forceinline__ void mmcolsum(const short* __restrict__ A,
                                         const short* __restrict__ Bm,
                                         float* scol, int tid) {
  int w = tid >> 6, lane = tid & 63, quad = lane >> 4, col = lane & 15;
  f32x4 acc[4];
#pragma unroll
  for (int j = 0; j < 4; j++) acc[j] = (f32x4){0.f, 0.f, 0.f, 0.f};
#pragma unroll
  for (int ks = 0; ks < 2; ks++) {
    int k0 = ks * 32 + quad * 8;
    bf16x8 fa = *(const bf16x8*)(A + (w * 16 + col) * 64 + k0);
#pragma unroll
    for (int j = 0; j < 4; j++) {
      bf16x8 fb = *(const bf16x8*)(Bm + (j * 16 + col) * 64 + k0);
      acc[j] = __builtin_amdgcn_mfma_f32_16x16x32_bf16(fa, fb, acc[j], 0, 0, 0);
    }
  }
#pragma unroll
  for (int j = 0; j < 4; j++) {
    float t = (acc[j][0] + acc[j][1]) + (acc[j][2] + acc[j][3]);
    atomicAdd(&scol[j * 16 + col], t);  // LDS atomic: sums all 64 rows
  }
}

// NS + gate-MLP tail. Reads per-(b,chunk) partials pg[(b*16+c)*4096],
// ps[(b*16+c)*256] with plain (cached) vectorized loads.
__device__ __forceinline__ void ns_tail(unsigned char* smem, int b, int tid,
                                        const float* __restrict__ pg,
                                        const float* __restrict__ ps,
                                        const float* __restrict__ w1,
                                        const float* __restrict__ pb1,
                                        const float* __restrict__ w2,
                                        const float* __restrict__ pb2,
                                        float* __restrict__ gatews) {
  short* nb0 = (short*)smem;             // 5 x 8 KB bf16 64x64 buffers
  short* nb1 = nb0 + 4096;
  short* nb2 = nb0 + 8192;
  short* nb3 = nb0 + 12288;
  short* nb4 = nb0 + 16384;
  float* gsum = (float*)(smem + 40960);  // 16 KB
  float* mu = (float*)(smem + 57344);
  float* scol = (float*)(smem + 57600);
  float* hbuf = (float*)(smem + 57856);
  float* pnorm = (float*)(smem + 57888);

  {
    const float* pgb = pg + (size_t)b * NCHUNKS * 4096;
#pragma unroll
    for (int e = 0; e < 16; e++) {
      int idx = tid + 256 * e;
      float s = 0.f;
#pragma unroll
      for (int c = 0; c < NCHUNKS; c++) s += pgb[c * 4096 + idx];
      gsum[idx] = s;
    }
    if (tid < 64) {
      const float* psb = ps + (size_t)b * NCHUNKS * 256;
      float s = 0.f;
#pragma unroll
      for (int c = 0; c < NCHUNKS; c++)
#pragma unroll
        for (int sub = 0; sub < 4; sub++) s += psb[c * 256 + sub * 64 + tid];
      mu[tid] = s * (1.0f / MM);
    }
  }
  __syncthreads();

  if (tid < 64) {
    float d = gsum[tid * 65] * (1.0f / MM) - mu[tid] * mu[tid];
#pragma unroll
    for (int off = 32; off >= 1; off >>= 1) d += __shfl_down(d, off);
    if (tid == 0) *pnorm = d;
  }
  __syncthreads();
  float normA = *pnorm;
  float rn = 1.0f / normA;
  // A -> nb0, Z = ZY0 = 1.5I - 0.5A -> nb1
#pragma unroll
  for (int e = 0; e < 16; e++) {
    int idx = tid + 256 * e;
    int r = idx >> 6, c = idx & 63;
    float cv = gsum[idx] * (1.0f / MM) - mu[r] * mu[c];
    float a = cv * rn;
    nb0[idx] = f2bf(a);
    nb1[idx] = f2bf((r == c ? 1.5f : 0.0f) - 0.5f * a);
  }
  __syncthreads();
  mm64(nb2, nb0, nb1, tid);  // Y = A @ ZY0
  __syncthreads();
  short *pY = nb2, *pZ = nb1, *s0 = nb3, *s1 = nb4, *s2 = nb0;
  for (int it = 0; it < 3; ++it) {
    // T = 1.5I - 0.5 Z -> s0
#pragma unroll
    for (int e = 0; e < 16; e++) {
      int idx = tid + 256 * e;
      int r = idx >> 6, c = idx & 63;
      float z = bf2f(pZ[idx]);
      s0[idx] = f2bf((r == c ? 1.5f : 0.0f) - 0.5f * z);
    }
    __syncthreads();
    mm64(s1, s0, pY, tid);  // W = T @ Y
    __syncthreads();
    mm64(s2, pY, s1, tid);  // Ynew = Y @ W
    mm64(s0, s1, pZ, tid);  // Znew = W @ Z  (overwrites T; W-matmul already fenced)
    __syncthreads();
    short* oY = pY; short* oZ = pZ; short* oW = s1;
    pY = s2; pZ = s0; s0 = oY; s1 = oZ; s2 = oW;
  }
  mm64(s0, pZ, pY, tid);  // P = Z @ Y
  __syncthreads();
#pragma unroll
  for (int e = 0; e < 16; e++) {  // s0 = 3I - P (in place, own elements only)
    int idx = tid + 256 * e;
    int r = idx >> 6, c = idx & 63;
    float p = bf2f(s0[idx]);
    s0[idx] = f2bf((r == c ? 3.0f : 0.0f) - p);
  }
  if (tid < 64) scol[tid] = 0.0f;
  __syncthreads();
  mmcolsum(pY, s0, scol, tid);  // column sums of R = Y @ (3I - P)
  __syncthreads();
  if (tid < 8) {
    float sc = 0.5f * sqrtf(normA) * (1.0f / 64.0f);
    float acc2 = pb1[tid];
    for (int c = 0; c < 64; c++) acc2 += scol[c] * sc * w1[tid * 64 + c];
    hbuf[tid] = fmaxf(acc2, 0.0f);
  }
  __syncthreads();
  if (tid < 64) {
    float acc2 = pb2[tid];
#pragma unroll
    for (int j = 0; j < 8; j++) acc2 += hbuf[j] * w2[tid * 8 + j];
    gatews[b * 64 + tid] = 1.0f / (1.0f + __expf(-acc2));
  }
}

// ---------------- K1: fused gram + (last-arrival) NS ----------------
// 512 blocks x 256 threads, exactly 64 KB static LDS -> 2 blocks/CU.
__global__ __launch_bounds__(256, 2) void gramns_k(
    const float* __restrict__ x, float* __restrict__ pg, float* __restrict__ ps,
    int* __restrict__ ctr, const float* __restrict__ w1,
    const float* __restrict__ pb1, const float* __restrict__ w2,
    const float* __restrict__ pb2, float* __restrict__ gatews) {
  __shared__ __align__(16) unsigned char smem[65536];
  float(*red)[4096] = reinterpret_cast<float(*)[4096]>(smem);

  int b = blockIdx.x / NCHUNKS;
  int chunk = blockIdx.x % NCHUNKS;
  int tid = threadIdx.x;
  int w = tid >> 6, lane = tid & 63;
  int quad = lane >> 4, col = lane & 15;
  const float* xb = x + (size_t)b * CC * MM;

  f32x4 acc[4][4];
#pragma unroll
  for (int i = 0; i < 4; i++)
#pragma unroll
    for (int j = 0; j < 4; j++) acc[i][j] = (f32x4){0.f, 0.f, 0.f, 0.f};
  float csum[4] = {0.f, 0.f, 0.f, 0.f};

  // chunks 0-7: 5 steps (640 m per block), chunks 8-15: 4 steps (512 m)
  if (chunk < 8) {
    int mwave = chunk * 640 + w * (5 * 32);
    gram_body<5>(xb, mwave, quad, col, acc, csum);
  } else {
    int mwave = 5120 + (chunk - 8) * 512 + w * (4 * 32);
    gram_body<4>(xb, mwave, quad, col, acc, csum);
  }

  // per-wave channel sums -> global (plain stores; no LDS needed)
#pragma unroll
  for (int rb = 0; rb < 4; rb++) {
    float c0 = csum[rb];
    c0 += __shfl_xor(c0, 16);
    c0 += __shfl_xor(c0, 32);
    if (lane < 16)
      ps[(size_t)blockIdx.x * 256 + w * 64 + rb * 16 + lane] = c0;
  }

  // block-level reduce of the 4 waves' partial Grams -> plain stores
#pragma unroll
  for (int i = 0; i < 4; i++)
#pragma unroll
    for (int j = 0; j < 4; j++)
#pragma unroll
      for (int r = 0; r < 4; r++)
        red[w][(i * 16 + quad * 4 + r) * 64 + j * 16 + col] = acc[i][j][r];
  __syncthreads();
  float* covb = pg + (size_t)blockIdx.x * 4096;
#pragma unroll
  for (int e = 0; e < 16; e++) {
    int idx = tid + 256 * e;
    covb[idx] = (red[0][idx] + red[1][idx]) + (red[2][idx] + red[3][idx]);
  }

  // -------- last-arrival election (no waiting; deadlock-free) --------
  __threadfence();   // each thread releases its own stores at device scope
  __syncthreads();   // red[] reads done; all threads fenced
  volatile int* pold = (int*)smem;  // overlays red[0][0]; red no longer needed
  if (tid == 0)
    *pold = __hip_atomic_fetch_add(ctr + b, 1, __ATOMIC_ACQ_REL,
                                   __HIP_MEMORY_SCOPE_AGENT);
  __syncthreads();
  if (*pold != NCHUNKS - 1) return;  // not the last block for this batch
  __threadfence();  // acquire side for ALL winner threads (invalidate caches)
  __syncthreads();

  ns_tail(smem, b, tid, pg, ps, w1, pb1, w2, pb2, gatews);
}

// ---------------- K2: out = x * gate ----------------
// One block per (b,c): gate value is wave-uniform (SGPR), accesses fully
// coalesced. 2048 blocks x 256 threads x 9 float4 = whole tensor.
__global__ __launch_bounds__(256) void gate_mul(const float* __restrict__ x,
                                                const float* __restrict__ gatews,
                                                float* __restrict__ out) {
  int bc = blockIdx.x;
  float g = gatews[bc];
  const float4* xp = (const float4*)(x + (size_t)bc * MM);
  float4* op = (float4*)(out + (size_t)bc * MM);
  int t = threadIdx.x;
#pragma unroll
  for (int it = 0; it < 9; ++it) {
    float4 v = xp[t + it * 256];
    v.x *= g; v.y *= g; v.z *= g; v.w *= g;
    op[t + it * 256] = v;
  }
}

// ================= fallback: proven 3-kernel plain-store path =============
__global__ __launch_bounds__(256, 2) void gram_k_leg(const float* __restrict__ x,
                                                     float* __restrict__ pg,
                                                     float* __restrict__ ps) {
  int b = blockIdx.x / NCHUNKS;
  int chunk = blockIdx.x % NCHUNKS;
  int tid = threadIdx.x;
  int w = tid >> 6, lane = tid & 63;
  int quad = lane >> 4, col = lane & 15;
  const float* xb = x + (size_t)b * CC * MM;

  f32x4 acc[4][4];
#pragma unroll
  for (int i = 0; i < 4; i++)
#pragma unroll
    for (int j = 0; j < 4; j++) acc[i][j] = (f32x4){0.f, 0.f, 0.f, 0.f};
  float csum[4] = {0.f, 0.f, 0.f, 0.f};
  if (chunk < 8) {
    int mwave = chunk * 640 + w * (5 * 32);
    gram_body<5>(xb, mwave, quad, col, acc, csum);
  } else {
    int mwave = 5120 + (chunk - 8) * 512 + w * (4 * 32);
    gram_body<4>(xb, mwave, quad, col, acc, csum);
  }
#pragma unroll
  for (int rb = 0; rb < 4; rb++) {
    float c0 = csum[rb];
    c0 += __shfl_xor(c0, 16);
    c0 += __shfl_xor(c0, 32);
    if (lane < 16)
      ps[(size_t)blockIdx.x * 256 + w * 64 + rb * 16 + lane] = c0;
  }
  __shared__ float red[4][4096];
#pragma unroll
  for (int i = 0; i < 4; i++)
#pragma unroll
    for (int j = 0; j < 4; j++)
#pragma unroll
      for (int r = 0; r < 4; r++)
        red[w][(i * 16 + quad * 4 + r) * 64 + j * 16 + col] = acc[i][j][r];
  __syncthreads();
  float* covb = pg + (size_t)blockIdx.x * 4096;
#pragma unroll
  for (int e = 0; e < 16; e++) {
    int idx = tid + 256 * e;
    covb[idx] = (red[0][idx] + red[1][idx]) + (red[2][idx] + red[3][idx]);
  }
}

__global__ __launch_bounds__(256) void ns_k_leg(const float* __restrict__ pg,
                                                const float* __restrict__ ps,
                                                const float* __restrict__ w1,
                                                const float* __restrict__ pb1,
                                                const float* __restrict__ w2,
                                                const float* __restrict__ pb2,
                                                float* __restrict__ gatews) {
  __shared__ __align__(16) unsigned char smem[60416];
  ns_tail(smem, blockIdx.x, threadIdx.x, pg, ps, w1, pb1, w2, pb2, gatews);
}

extern "C" void kernel_launch(void* const* d_in, const int* in_sizes, int n_in,
                              void* d_out, int out_size, void* d_ws, size_t ws_size,
                              hipStream_t stream) {
  const float* x = (const float*)d_in[0];
  const float* w1 = (const float*)d_in[1];
  const float* b1 = (const float*)d_in[2];
  const float* w2 = (const float*)d_in[3];
  const float* b2 = (const float*)d_in[4];
  float* out = (float*)d_out;
  float* ws = (float*)d_ws;

  const size_t NPG = (size_t)BB * NCHUNKS * 4096;  // 2M floats = 8 MB
  const size_t NPS = (size_t)BB * NCHUNKS * 256;   // 128K floats = 512 KB
  float* pg = ws;
  float* psum = ws + NPG;
  int* ctr = (int*)(psum + NPS);        // 32 ints
  float* gatews = (float*)(ctr + BB);   // 2048 fp32 (fully rewritten each run)
  const size_t needP = (NPG + NPS + BB + BB * CC) * sizeof(float);

  if (ws_size >= needP) {
    hipMemsetAsync(ctr, 0, BB * sizeof(int), stream);  // 128 B
    gramns_k<<<BB * NCHUNKS, 256, 0, stream>>>(x, pg, psum, ctr, w1, b1, w2,
                                               b2, gatews);
    gate_mul<<<BB * CC, 256, 0, stream>>>(x, gatews, out);
  } else {
    // 3-kernel fallback (no election) -- requires only the same buffers
    gram_k_leg<<<BB * NCHUNKS, 256, 0, stream>>>(x, pg, psum);
    ns_k_leg<<<BB, 256, 0, stream>>>(pg, psum, w1, b1, w2, b2, gatews);
    gate_mul<<<BB * CC, 256, 0, stream>>>(x, gatews, out);
  }
}

// Round 8
// 174.739 us; speedup vs baseline: 1.5055x; 1.5055x over previous
//
#include <hip/hip_runtime.h>
#include <math.h>

// SecondOrderChannelAttension on MI355X (gfx950)
// B=32, C=64, H=W=96 -> M=9216, RED=8
//
// THREE dispatches, fence-free cross-block handoff:
//   memset  : zero 32 election counters in ws (128 B). REQUIRED every call:
//             the harness poisons d_ws between timed graph replays (round 6
//             failed by keeping counters in d_out, which isn't re-zeroed).
//   K1 gramns_k (512 blocks): per-(batch,chunk) partial Gram via bf16 MFMA +
//      channel sums. Partials published with WRITE-THROUGH stores (agent-scope
//      relaxed atomic stores -> sc1; never dirties L2, so no buffer_wbl2 is
//      needed -- the round-2/round-5 ~100us disaster was 512 blocks each doing
//      a device-scope release = full L2 writeback). Election via relaxed agent
//      fetch_add; the last-arriving block per batch does an ACQUIRE fence
//      (L2 *invalidate* -- cheap) and runs Newton-Schulz + gate MLP with
//      vectorized cached loads. No spin-waits -> deadlock-free.
//   K2 gate_mul (2048 blocks): out = x * gate, one block per (b,c) row.
//
// NOTE: hipLaunchCooperativeKernel is NOT graph-capturable here (round 4).
// NOTE: __threadfence() / release fences in wide kernels cost ~100us (r2,r5).
// NOTE: d_ws is POISONED between replays; d_out is NOT re-zeroed. Any
//       cross-call state must be explicitly initialized every launch.

#define BB 32
#define CC 64
#define MM 9216
#define NCHUNKS 16

typedef __attribute__((ext_vector_type(8))) short bf16x8;
typedef __attribute__((ext_vector_type(4))) float f32x4;

__device__ __forceinline__ short f2bf(float f) {
  unsigned u = __builtin_bit_cast(unsigned, f);
  return (short)(unsigned short)((u + 0x8000u) >> 16);  // round-half-up, fine here
}
__device__ __forceinline__ float bf2f(short h) {
  unsigned u = ((unsigned)(unsigned short)h) << 16;
  return __builtin_bit_cast(float, u);
}
// write-through (sc1) store: globally visible once vmcnt drains; no dirty L2.
__device__ __forceinline__ void wt_store(float* p, float v) {
  __hip_atomic_store(p, v, __ATOMIC_RELAXED, __HIP_MEMORY_SCOPE_AGENT);
}

// ---------------- gram inner loop ----------------
// Fragment trick: for Gram, the B-operand fragment (B[k][n] = X[n][k]) has the
// same lane mapping as the A fragment of X rows -> load once, use twice.
template <int NSTEP>
__device__ __forceinline__ void gram_body(const float* __restrict__ xb, int mwave,
                                          int quad, int col,
                                          f32x4 acc[4][4], float csum[4]) {
  const float* base[4];
#pragma unroll
  for (int rb = 0; rb < 4; rb++)
    base[rb] = xb + (size_t)(rb * 16 + col) * MM + mwave + quad * 8;

  float4 cur[4][2];
#pragma unroll
  for (int rb = 0; rb < 4; rb++) {
    cur[rb][0] = *(const float4*)(base[rb]);
    cur[rb][1] = *(const float4*)(base[rb] + 4);
  }
#pragma unroll
  for (int s = 0; s < NSTEP; s++) {
    float4 nxt[4][2];
    if (s + 1 < NSTEP) {
#pragma unroll
      for (int rb = 0; rb < 4; rb++) {
        const float* p = base[rb] + (s + 1) * 32;
        nxt[rb][0] = *(const float4*)(p);
        nxt[rb][1] = *(const float4*)(p + 4);
      }
    }
    bf16x8 frag[4];
#pragma unroll
    for (int rb = 0; rb < 4; rb++) {
      float v0 = cur[rb][0].x, v1 = cur[rb][0].y, v2 = cur[rb][0].z, v3 = cur[rb][0].w;
      float v4 = cur[rb][1].x, v5 = cur[rb][1].y, v6 = cur[rb][1].z, v7 = cur[rb][1].w;
      csum[rb] += ((v0 + v1) + (v2 + v3)) + ((v4 + v5) + (v6 + v7));
      bf16x8 f;
      f[0] = f2bf(v0); f[1] = f2bf(v1); f[2] = f2bf(v2); f[3] = f2bf(v3);
      f[4] = f2bf(v4); f[5] = f2bf(v5); f[6] = f2bf(v6); f[7] = f2bf(v7);
      frag[rb] = f;
    }
#pragma unroll
    for (int i = 0; i < 4; i++)
#pragma unroll
      for (int j = 0; j < 4; j++)
        acc[i][j] = __builtin_amdgcn_mfma_f32_16x16x32_bf16(frag[i], frag[j],
                                                            acc[i][j], 0, 0, 0);
    if (s + 1 < NSTEP) {
#pragma unroll
      for (int rb = 0; rb < 4; rb++) {
        cur[rb][0] = nxt[rb][0];
        cur[rb][1] = nxt[rb][1];
      }
    }
  }
}

// ---------------- 64x64 NS matmuls (LDS, bf16 MFMA) ----------------
// All NS iterates are symmetric (polynomials in A), so row-major read serves
// as the k-major B fragment.
__device__ __forceinline__ void mm64(short* __restrict__ D, const short* __restrict__ A,
                                     const short* __restrict__ Bm, int tid) {
  int w = tid >> 6, lane = tid & 63, quad = lane >> 4, col = lane & 15;
  f32x4 acc[4];
#pragma unroll
  for (int j = 0; j < 4; j++) acc[j] = (f32x4){0.f, 0.f, 0.f, 0.f};
#pragma unroll
  for (int ks = 0; ks < 2; ks++) {
    int k0 = ks * 32 + quad * 8;
    bf16x8 fa = *(const bf16x8*)(A + (w * 16 + col) * 64 + k0);
#pragma unroll
    for (int j = 0; j < 4; j++) {
      bf16x8 fb = *(const bf16x8*)(Bm + (j * 16 + col) * 64 + k0);
      acc[j] = __builtin_amdgcn_mfma_f32_16x16x32_bf16(fa, fb, acc[j], 0, 0, 0);
    }
  }
#pragma unroll
  for (int j = 0; j < 4; j++)
#pragma unroll
    for (int r = 0; r < 4; r++)
      D[(w * 16 + quad * 4 + r) * 64 + j * 16 + col] = f2bf(acc[j][r]);
}

__device__ __forceinline__ void mmcolsum(const short* __restrict__ A,
                                         const short* __restrict__ Bm,
                                         float* scol, int tid) {
  int w = tid >> 6, lane = tid & 63, quad = lane >> 4, col = lane & 15;
  f32x4 acc[4];
#pragma unroll
  for (int j = 0; j < 4; j++) acc[j] = (f32x4){0.f, 0.f, 0.f, 0.f};
#pragma unroll
  for (int ks = 0; ks < 2; ks++) {
    int k0 = ks * 32 + quad * 8;
    bf16x8 fa = *(const bf16x8*)(A + (w * 16 + col) * 64 + k0);
#pragma unroll
    for (int j = 0; j < 4; j++) {
      bf16x8 fb = *(const bf16x8*)(Bm + (j * 16 + col) * 64 + k0);
      acc[j] = __builtin_amdgcn_mfma_f32_16x16x32_bf16(fa, fb, acc[j], 0, 0, 0);
    }
  }
#pragma unroll
  for (int j = 0; j < 4; j++) {
    float t = (acc[j][0] + acc[j][1]) + (acc[j][2] + acc[j][3]);
    atomicAdd(&scol[j * 16 + col], t);  // LDS atomic: sums all 64 rows
  }
}

// NS + gate-MLP tail. Caller must have acquire-fenced (agent) so plain
// vectorized loads below see the write-through partials.
__device__ __forceinline__ void ns_tail(unsigned char* smem, int b, int tid,
                                        const float* __restrict__ pg,
                                        const float* __restrict__ ps,
                                        const float* __restrict__ w1,
                                        const float* __restrict__ pb1,
                                        const float* __restrict__ w2,
                                        const float* __restrict__ pb2,
                                        float* __restrict__ gatews) {
  short* nb0 = (short*)smem;             // 5 x 8 KB bf16 64x64 buffers
  short* nb1 = nb0 + 4096;
  short* nb2 = nb0 + 8192;
  short* nb3 = nb0 + 12288;
  short* nb4 = nb0 + 16384;
  float* gsum = (float*)(smem + 40960);  // 16 KB
  float* mu = (float*)(smem + 57344);
  float* scol = (float*)(smem + 57600);
  float* hbuf = (float*)(smem + 57856);
  float* pnorm = (float*)(smem + 57888);

  {
    // vectorized gather: independent float4 loads (NEVER scalar uncached
    // loads here -- that serialized round 2 into ~100us)
    const float4* pgb4 = (const float4*)(pg + (size_t)b * NCHUNKS * 4096);
    float4* gsum4 = (float4*)gsum;
#pragma unroll
    for (int e = 0; e < 4; e++) {
      int i4 = tid + 256 * e;
      float4 s = {0.f, 0.f, 0.f, 0.f};
#pragma unroll
      for (int c = 0; c < NCHUNKS; c++) {
        float4 v = pgb4[c * 1024 + i4];
        s.x += v.x; s.y += v.y; s.z += v.z; s.w += v.w;
      }
      gsum4[i4] = s;
    }
    if (tid < 64) {
      const float* psb = ps + (size_t)b * NCHUNKS * 256;
      float s = 0.f;
#pragma unroll
      for (int c = 0; c < NCHUNKS; c++)
#pragma unroll
        for (int sub = 0; sub < 4; sub++) s += psb[c * 256 + sub * 64 + tid];
      mu[tid] = s * (1.0f / MM);
    }
  }
  __syncthreads();

  if (tid < 64) {
    float d = gsum[tid * 65] * (1.0f / MM) - mu[tid] * mu[tid];
#pragma unroll
    for (int off = 32; off >= 1; off >>= 1) d += __shfl_down(d, off);
    if (tid == 0) *pnorm = d;
  }
  __syncthreads();
  float normA = *pnorm;
  float rn = 1.0f / normA;
  // A -> nb0, Z = ZY0 = 1.5I - 0.5A -> nb1
#pragma unroll
  for (int e = 0; e < 16; e++) {
    int idx = tid + 256 * e;
    int r = idx >> 6, c = idx & 63;
    float cv = gsum[idx] * (1.0f / MM) - mu[r] * mu[c];
    float a = cv * rn;
    nb0[idx] = f2bf(a);
    nb1[idx] = f2bf((r == c ? 1.5f : 0.0f) - 0.5f * a);
  }
  __syncthreads();
  mm64(nb2, nb0, nb1, tid);  // Y = A @ ZY0
  __syncthreads();
  short *pY = nb2, *pZ = nb1, *s0 = nb3, *s1 = nb4, *s2 = nb0;
  for (int it = 0; it < 3; ++it) {
    // T = 1.5I - 0.5 Z -> s0
#pragma unroll
    for (int e = 0; e < 16; e++) {
      int idx = tid + 256 * e;
      int r = idx >> 6, c = idx & 63;
      float z = bf2f(pZ[idx]);
      s0[idx] = f2bf((r == c ? 1.5f : 0.0f) - 0.5f * z);
    }
    __syncthreads();
    mm64(s1, s0, pY, tid);  // W = T @ Y
    __syncthreads();
    mm64(s2, pY, s1, tid);  // Ynew = Y @ W
    mm64(s0, s1, pZ, tid);  // Znew = W @ Z  (overwrites T; W-matmul already fenced)
    __syncthreads();
    short* oY = pY; short* oZ = pZ; short* oW = s1;
    pY = s2; pZ = s0; s0 = oY; s1 = oZ; s2 = oW;
  }
  mm64(s0, pZ, pY, tid);  // P = Z @ Y
  __syncthreads();
#pragma unroll
  for (int e = 0; e < 16; e++) {  // s0 = 3I - P (in place, own elements only)
    int idx = tid + 256 * e;
    int r = idx >> 6, c = idx & 63;
    float p = bf2f(s0[idx]);
    s0[idx] = f2bf((r == c ? 3.0f : 0.0f) - p);
  }
  if (tid < 64) scol[tid] = 0.0f;
  __syncthreads();
  mmcolsum(pY, s0, scol, tid);  // column sums of R = Y @ (3I - P)
  __syncthreads();
  if (tid < 8) {
    float sc = 0.5f * sqrtf(normA) * (1.0f / 64.0f);
    float acc2 = pb1[tid];
    for (int c = 0; c < 64; c++) acc2 += scol[c] * sc * w1[tid * 64 + c];
    hbuf[tid] = fmaxf(acc2, 0.0f);
  }
  __syncthreads();
  if (tid < 64) {
    float acc2 = pb2[tid];
#pragma unroll
    for (int j = 0; j < 8; j++) acc2 += hbuf[j] * w2[tid * 8 + j];
    gatews[b * 64 + tid] = 1.0f / (1.0f + __expf(-acc2));
  }
}

// ---------------- K1: fused gram + fence-free last-arrival NS ----------------
// 512 blocks x 256 threads, exactly 64 KB static LDS -> 2 blocks/CU.
__global__ __launch_bounds__(256, 2) void gramns_k(
    const float* __restrict__ x, float* __restrict__ pg, float* __restrict__ ps,
    int* __restrict__ ctr, const float* __restrict__ w1,
    const float* __restrict__ pb1, const float* __restrict__ w2,
    const float* __restrict__ pb2, float* __restrict__ gatews) {
  __shared__ __align__(16) unsigned char smem[65536];
  float(*red)[4096] = reinterpret_cast<float(*)[4096]>(smem);

  int b = blockIdx.x / NCHUNKS;
  int chunk = blockIdx.x % NCHUNKS;
  int tid = threadIdx.x;
  int w = tid >> 6, lane = tid & 63;
  int quad = lane >> 4, col = lane & 15;
  const float* xb = x + (size_t)b * CC * MM;

  f32x4 acc[4][4];
#pragma unroll
  for (int i = 0; i < 4; i++)
#pragma unroll
    for (int j = 0; j < 4; j++) acc[i][j] = (f32x4){0.f, 0.f, 0.f, 0.f};
  float csum[4] = {0.f, 0.f, 0.f, 0.f};

  // chunks 0-7: 5 steps (640 m per block), chunks 8-15: 4 steps (512 m)
  if (chunk < 8) {
    int mwave = chunk * 640 + w * (5 * 32);
    gram_body<5>(xb, mwave, quad, col, acc, csum);
  } else {
    int mwave = 5120 + (chunk - 8) * 512 + w * (4 * 32);
    gram_body<4>(xb, mwave, quad, col, acc, csum);
  }

  // per-wave channel sums -> write-through stores
#pragma unroll
  for (int rb = 0; rb < 4; rb++) {
    float c0 = csum[rb];
    c0 += __shfl_xor(c0, 16);
    c0 += __shfl_xor(c0, 32);
    if (lane < 16)
      wt_store(ps + (size_t)blockIdx.x * 256 + w * 64 + rb * 16 + lane, c0);
  }

  // block-level reduce of the 4 waves' partial Grams -> write-through stores
#pragma unroll
  for (int i = 0; i < 4; i++)
#pragma unroll
    for (int j = 0; j < 4; j++)
#pragma unroll
      for (int r = 0; r < 4; r++)
        red[w][(i * 16 + quad * 4 + r) * 64 + j * 16 + col] = acc[i][j][r];
  __syncthreads();
  float* covb = pg + (size_t)blockIdx.x * 4096;
#pragma unroll
  for (int e = 0; e < 16; e++) {
    int idx = tid + 256 * e;
    float v = (red[0][idx] + red[1][idx]) + (red[2][idx] + red[3][idx]);
    wt_store(covb + idx, v);
  }

  // -------- fence-free last-arrival election --------
  // __syncthreads drains vmcnt(0) per thread -> all write-through stores of
  // this block are globally visible before the counter increment.
  __syncthreads();
  volatile int* pold = (int*)smem;  // overlays red[0][0]; red no longer needed
  if (tid == 0)
    *pold = __hip_atomic_fetch_add(ctr + b, 1, __ATOMIC_RELAXED,
                                   __HIP_MEMORY_SCOPE_AGENT);
  __syncthreads();
  if (*pold != NCHUNKS - 1) return;  // not the last block for this batch

  // acquire at agent scope = L2 *invalidate* (cheap; NOT a writeback) so the
  // plain vectorized loads in ns_tail see the other XCDs' partials.
  __builtin_amdgcn_fence(__ATOMIC_ACQUIRE, "agent");
  ns_tail(smem, b, tid, pg, ps, w1, pb1, w2, pb2, gatews);
}

// ---------------- K2: out = x * gate ----------------
// One block per (b,c): gate value is wave-uniform (SGPR), accesses fully
// coalesced. 2048 blocks x 256 threads x 9 float4 = whole tensor.
__global__ __launch_bounds__(256) void gate_mul(const float* __restrict__ x,
                                                const float* __restrict__ gatews,
                                                float* __restrict__ out) {
  int bc = blockIdx.x;
  float g = gatews[bc];
  const float4* xp = (const float4*)(x + (size_t)bc * MM);
  float4* op = (float4*)(out + (size_t)bc * MM);
  int t = threadIdx.x;
#pragma unroll
  for (int it = 0; it < 9; ++it) {
    float4 v = xp[t + it * 256];
    v.x *= g; v.y *= g; v.z *= g; v.w *= g;
    op[t + it * 256] = v;
  }
}

// ================= fallback: proven 3-kernel plain-store path =============
__global__ __launch_bounds__(256, 2) void gram_k_leg(const float* __restrict__ x,
                                                     float* __restrict__ pg,
                                                     float* __restrict__ ps) {
  int b = blockIdx.x / NCHUNKS;
  int chunk = blockIdx.x % NCHUNKS;
  int tid = threadIdx.x;
  int w = tid >> 6, lane = tid & 63;
  int quad = lane >> 4, col = lane & 15;
  const float* xb = x + (size_t)b * CC * MM;

  f32x4 acc[4][4];
#pragma unroll
  for (int i = 0; i < 4; i++)
#pragma unroll
    for (int j = 0; j < 4; j++) acc[i][j] = (f32x4){0.f, 0.f, 0.f, 0.f};
  float csum[4] = {0.f, 0.f, 0.f, 0.f};
  if (chunk < 8) {
    int mwave = chunk * 640 + w * (5 * 32);
    gram_body<5>(xb, mwave, quad, col, acc, csum);
  } else {
    int mwave = 5120 + (chunk - 8) * 512 + w * (4 * 32);
    gram_body<4>(xb, mwave, quad, col, acc, csum);
  }
#pragma unroll
  for (int rb = 0; rb < 4; rb++) {
    float c0 = csum[rb];
    c0 += __shfl_xor(c0, 16);
    c0 += __shfl_xor(c0, 32);
    if (lane < 16)
      ps[(size_t)blockIdx.x * 256 + w * 64 + rb * 16 + lane] = c0;
  }
  __shared__ float red[4][4096];
#pragma unroll
  for (int i = 0; i < 4; i++)
#pragma unroll
    for (int j = 0; j < 4; j++)
#pragma unroll
      for (int r = 0; r < 4; r++)
        red[w][(i * 16 + quad * 4 + r) * 64 + j * 16 + col] = acc[i][j][r];
  __syncthreads();
  float* covb = pg + (size_t)blockIdx.x * 4096;
#pragma unroll
  for (int e = 0; e < 16; e++) {
    int idx = tid + 256 * e;
    covb[idx] = (red[0][idx] + red[1][idx]) + (red[2][idx] + red[3][idx]);
  }
}

__global__ __launch_bounds__(256) void ns_k_leg(const float* __restrict__ pg,
                                                const float* __restrict__ ps,
                                                const float* __restrict__ w1,
                                                const float* __restrict__ pb1,
                                                const float* __restrict__ w2,
                                                const float* __restrict__ pb2,
                                                float* __restrict__ gatews) {
  __shared__ __align__(16) unsigned char smem[60416];
  ns_tail(smem, blockIdx.x, threadIdx.x, pg, ps, w1, pb1, w2, pb2, gatews);
}

extern "C" void kernel_launch(void* const* d_in, const int* in_sizes, int n_in,
                              void* d_out, int out_size, void* d_ws, size_t ws_size,
                              hipStream_t stream) {
  const float* x = (const float*)d_in[0];
  const float* w1 = (const float*)d_in[1];
  const float* b1 = (const float*)d_in[2];
  const float* w2 = (const float*)d_in[3];
  const float* b2 = (const float*)d_in[4];
  float* out = (float*)d_out;
  float* ws = (float*)d_ws;

  const size_t NPG = (size_t)BB * NCHUNKS * 4096;  // 2M floats = 8 MB
  const size_t NPS = (size_t)BB * NCHUNKS * 256;   // 128K floats = 512 KB
  float* pg = ws;
  float* psum = ws + NPG;
  float* gatews = psum + NPS;          // 2048 fp32, rewritten every call
  int* ctr = (int*)(gatews + BB * CC); // 32 ints, memset every call
  const size_t needP = (NPG + NPS + BB * CC + BB) * sizeof(float);

  if (ws_size >= needP) {
    hipMemsetAsync(ctr, 0, BB * sizeof(int), stream);  // 128 B, mandatory
    gramns_k<<<BB * NCHUNKS, 256, 0, stream>>>(x, pg, psum, ctr, w1, b1, w2,
                                               b2, gatews);
    gate_mul<<<BB * CC, 256, 0, stream>>>(x, gatews, out);
  } else {
    // 3-kernel fallback (no election)
    gram_k_leg<<<BB * NCHUNKS, 256, 0, stream>>>(x, pg, psum);
    ns_k_leg<<<BB, 256, 0, stream>>>(pg, psum, w1, b1, w2, b2, gatews);
    gate_mul<<<BB * CC, 256, 0, stream>>>(x, gatews, out);
  }
}

// Round 9
// 169.263 us; speedup vs baseline: 1.5542x; 1.0323x over previous
//
#include <hip/hip_runtime.h>
#include <math.h>

// SecondOrderChannelAttension on MI355X (gfx950)
// B=32, C=64, H=W=96 -> M=9216, RED=8
//
// TWO dispatches:
//   memset  : zero 32 election counters + 32 gate-ready flags (256 B).
//             Mandatory every call (d_ws is poisoned between graph replays).
//   fused_k (512 blocks, 2/CU, 64 KB LDS): per-(batch,chunk) partial Gram via
//     bf16 MFMA -> publish partials with WRITE-THROUGH stores (agent-scope
//     relaxed atomic stores; never dirties L2 -> no buffer_wbl2; the
//     round-2/5 ~100us disaster was per-block release fences = L2 writeback).
//     Election: relaxed agent fetch_add. Winner (last of its batch) gathers
//     partials with 8B relaxed agent ATOMIC loads (reach the coherence point
//     directly -> NO acquire fence -> nobody's L2 is invalidated, x stays
//     hot), runs Newton-Schulz + gate MLP, publishes the 256 B gate
//     (write-through) + a ready flag. Non-winners spin on the flag (tid0
//     only, s_sleep backoff) then read the gate via agent atomic loads.
//     Finally EVERY block multiplies its own x-chunk (L2-warm from the gram
//     read) by the gate and writes out. Deadlock safety: 512 blocks at 2/CU
//     (64KB LDS, ~104 VGPR) = full residency; in-order dispatch keeps each
//     batch's 16 publishers co-scheduled; counters memset'd every call.
//
// NOTE: hipLaunchCooperativeKernel is NOT graph-capturable here (round 4).
// NOTE: __threadfence()/release fences in wide kernels cost ~100us (r2,r5).
// NOTE: d_ws is POISONED between replays; d_out is NOT re-zeroed (round 6).
// Measured r8: gram phase ~35-40us (3x its BW roofline, all pipes idle);
// gate_mul standalone 25us (at roofline). This round removes gate's HBM
// re-read + one boundary; gram stall is next if structure is exhausted.

#define BB 32
#define CC 64
#define MM 9216
#define NCHUNKS 16

typedef __attribute__((ext_vector_type(8))) short bf16x8;
typedef __attribute__((ext_vector_type(4))) float f32x4;

__device__ __forceinline__ short f2bf(float f) {
  unsigned u = __builtin_bit_cast(unsigned, f);
  return (short)(unsigned short)((u + 0x8000u) >> 16);  // round-half-up, fine here
}
__device__ __forceinline__ float bf2f(short h) {
  unsigned u = ((unsigned)(unsigned short)h) << 16;
  return __builtin_bit_cast(float, u);
}
// write-through (agent-scope) store: visible at coherence point once vmcnt
// drains; no dirty L2 line anywhere.
__device__ __forceinline__ void wt_store(float* p, float v) {
  __hip_atomic_store(p, v, __ATOMIC_RELAXED, __HIP_MEMORY_SCOPE_AGENT);
}
// agent-scope relaxed atomic loads: read the coherence point (correct without
// any fence; do NOT invalidate local caches).
__device__ __forceinline__ float ag_load(const float* p) {
  return __hip_atomic_load(p, __ATOMIC_RELAXED, __HIP_MEMORY_SCOPE_AGENT);
}
__device__ __forceinline__ float2 ag_load2(const float* p) {
  unsigned long long u = __hip_atomic_load((const unsigned long long*)p,
                                           __ATOMIC_RELAXED,
                                           __HIP_MEMORY_SCOPE_AGENT);
  return __builtin_bit_cast(float2, u);
}

// ---------------- gram inner loop ----------------
// Fragment trick: for Gram, the B-operand fragment (B[k][n] = X[n][k]) has the
// same lane mapping as the A fragment of X rows -> load once, use twice.
template <int NSTEP>
__device__ __forceinline__ void gram_body(const float* __restrict__ xb, int mwave,
                                          int quad, int col,
                                          f32x4 acc[4][4], float csum[4]) {
  const float* base[4];
#pragma unroll
  for (int rb = 0; rb < 4; rb++)
    base[rb] = xb + (size_t)(rb * 16 + col) * MM + mwave + quad * 8;

  float4 cur[4][2];
#pragma unroll
  for (int rb = 0; rb < 4; rb++) {
    cur[rb][0] = *(const float4*)(base[rb]);
    cur[rb][1] = *(const float4*)(base[rb] + 4);
  }
#pragma unroll
  for (int s = 0; s < NSTEP; s++) {
    float4 nxt[4][2];
    if (s + 1 < NSTEP) {
#pragma unroll
      for (int rb = 0; rb < 4; rb++) {
        const float* p = base[rb] + (s + 1) * 32;
        nxt[rb][0] = *(const float4*)(p);
        nxt[rb][1] = *(const float4*)(p + 4);
      }
    }
    bf16x8 frag[4];
#pragma unroll
    for (int rb = 0; rb < 4; rb++) {
      float v0 = cur[rb][0].x, v1 = cur[rb][0].y, v2 = cur[rb][0].z, v3 = cur[rb][0].w;
      float v4 = cur[rb][1].x, v5 = cur[rb][1].y, v6 = cur[rb][1].z, v7 = cur[rb][1].w;
      csum[rb] += ((v0 + v1) + (v2 + v3)) + ((v4 + v5) + (v6 + v7));
      bf16x8 f;
      f[0] = f2bf(v0); f[1] = f2bf(v1); f[2] = f2bf(v2); f[3] = f2bf(v3);
      f[4] = f2bf(v4); f[5] = f2bf(v5); f[6] = f2bf(v6); f[7] = f2bf(v7);
      frag[rb] = f;
    }
#pragma unroll
    for (int i = 0; i < 4; i++)
#pragma unroll
      for (int j = 0; j < 4; j++)
        acc[i][j] = __builtin_amdgcn_mfma_f32_16x16x32_bf16(frag[i], frag[j],
                                                            acc[i][j], 0, 0, 0);
    if (s + 1 < NSTEP) {
#pragma unroll
      for (int rb = 0; rb < 4; rb++) {
        cur[rb][0] = nxt[rb][0];
        cur[rb][1] = nxt[rb][1];
      }
    }
  }
}

// ---------------- 64x64 NS matmuls (LDS, bf16 MFMA) ----------------
// All NS iterates are symmetric (polynomials in A), so row-major read serves
// as the k-major B fragment.
__device__ __forceinline__ void mm64(short* __restrict__ D, const short* __restrict__ A,
                                     const short* __restrict__ Bm, int tid) {
  int w = tid >> 6, lane = tid & 63, quad = lane >> 4, col = lane & 15;
  f32x4 acc[4];
#pragma unroll
  for (int j = 0; j < 4; j++) acc[j] = (f32x4){0.f, 0.f, 0.f, 0.f};
#pragma unroll
  for (int ks = 0; ks < 2; ks++) {
    int k0 = ks * 32 + quad * 8;
    bf16x8 fa = *(const bf16x8*)(A + (w * 16 + col) * 64 + k0);
#pragma unroll
    for (int j = 0; j < 4; j++) {
      bf16x8 fb = *(const bf16x8*)(Bm + (j * 16 + col) * 64 + k0);
      acc[j] = __builtin_amdgcn_mfma_f32_16x16x32_bf16(fa, fb, acc[j], 0, 0, 0);
    }
  }
#pragma unroll
  for (int j = 0; j < 4; j++)
#pragma unroll
    for (int r = 0; r < 4; r++)
      D[(w * 16 + quad * 4 + r) * 64 + j * 16 + col] = f2bf(acc[j][r]);
}

__device__ __forceinline__ void mmcolsum(const short* __restrict__ A,
                                         const short* __restrict__ Bm,
                                         float* scol, int tid) {
  int w = tid >> 6, lane = tid & 63, quad = lane >> 4, col = lane & 15;
  f32x4 acc[4];
#pragma unroll
  for (int j = 0; j < 4; j++) acc[j] = (f32x4){0.f, 0.f, 0.f, 0.f};
#pragma unroll
  for (int ks = 0; ks < 2; ks++) {
    int k0 = ks * 32 + quad * 8;
    bf16x8 fa = *(const bf16x8*)(A + (w * 16 + col) * 64 + k0);
#pragma unroll
    for (int j = 0; j < 4; j++) {
      bf16x8 fb = *(const bf16x8*)(Bm + (j * 16 + col) * 64 + k0);
      acc[j] = __builtin_amdgcn_mfma_f32_16x16x32_bf16(fa, fb, acc[j], 0, 0, 0);
    }
  }
#pragma unroll
  for (int j = 0; j < 4; j++) {
    float t = (acc[j][0] + acc[j][1]) + (acc[j][2] + acc[j][3]);
    atomicAdd(&scol[j * 16 + col], t);  // LDS atomic: sums all 64 rows
  }
}

#define GATE_SH_OFF 57920

// NS + gate-MLP tail. Gathers partials with agent atomic loads (no fence
// needed, caches untouched). Fills gate_sh (LDS) AND gatews (write-through).
__device__ __forceinline__ void ns_tail(unsigned char* smem, int b, int tid,
                                        const float* __restrict__ pg,
                                        const float* __restrict__ ps,
                                        const float* __restrict__ w1,
                                        const float* __restrict__ pb1,
                                        const float* __restrict__ w2,
                                        const float* __restrict__ pb2,
                                        float* __restrict__ gatews) {
  short* nb0 = (short*)smem;             // 5 x 8 KB bf16 64x64 buffers
  short* nb1 = nb0 + 4096;
  short* nb2 = nb0 + 8192;
  short* nb3 = nb0 + 12288;
  short* nb4 = nb0 + 16384;
  float* gsum = (float*)(smem + 40960);  // 16 KB
  float* mu = (float*)(smem + 57344);
  float* scol = (float*)(smem + 57600);
  float* hbuf = (float*)(smem + 57856);
  float* pnorm = (float*)(smem + 57888);
  float* gate_sh = (float*)(smem + GATE_SH_OFF);

  {
    // gather: 8B agent atomic loads, independent -> pipelined
    const float* pgb = pg + (size_t)b * NCHUNKS * 4096;
#pragma unroll
    for (int e = 0; e < 8; e++) {
      int i2 = tid + 256 * e;  // float2 index, 0..2047
      float sx = 0.f, sy = 0.f;
#pragma unroll
      for (int c = 0; c < NCHUNKS; c++) {
        float2 v = ag_load2(pgb + c * 4096 + 2 * i2);
        sx += v.x; sy += v.y;
      }
      gsum[2 * i2] = sx;
      gsum[2 * i2 + 1] = sy;
    }
    if (tid < 64) {
      const float* psb = ps + (size_t)b * NCHUNKS * 256;
      float s = 0.f;
#pragma unroll
      for (int c = 0; c < NCHUNKS; c++)
#pragma unroll
        for (int sub = 0; sub < 4; sub++)
          s += ag_load(psb + c * 256 + sub * 64 + tid);
      mu[tid] = s * (1.0f / MM);
    }
  }
  __syncthreads();

  if (tid < 64) {
    float d = gsum[tid * 65] * (1.0f / MM) - mu[tid] * mu[tid];
#pragma unroll
    for (int off = 32; off >= 1; off >>= 1) d += __shfl_down(d, off);
    if (tid == 0) *pnorm = d;
  }
  __syncthreads();
  float normA = *pnorm;
  float rn = 1.0f / normA;
  // A -> nb0, Z = ZY0 = 1.5I - 0.5A -> nb1
#pragma unroll
  for (int e = 0; e < 16; e++) {
    int idx = tid + 256 * e;
    int r = idx >> 6, c = idx & 63;
    float cv = gsum[idx] * (1.0f / MM) - mu[r] * mu[c];
    float a = cv * rn;
    nb0[idx] = f2bf(a);
    nb1[idx] = f2bf((r == c ? 1.5f : 0.0f) - 0.5f * a);
  }
  __syncthreads();
  mm64(nb2, nb0, nb1, tid);  // Y = A @ ZY0
  __syncthreads();
  short *pY = nb2, *pZ = nb1, *s0 = nb3, *s1 = nb4, *s2 = nb0;
  for (int it = 0; it < 3; ++it) {
    // T = 1.5I - 0.5 Z -> s0
#pragma unroll
    for (int e = 0; e < 16; e++) {
      int idx = tid + 256 * e;
      int r = idx >> 6, c = idx & 63;
      float z = bf2f(pZ[idx]);
      s0[idx] = f2bf((r == c ? 1.5f : 0.0f) - 0.5f * z);
    }
    __syncthreads();
    mm64(s1, s0, pY, tid);  // W = T @ Y
    __syncthreads();
    mm64(s2, pY, s1, tid);  // Ynew = Y @ W
    mm64(s0, s1, pZ, tid);  // Znew = W @ Z  (overwrites T; W-matmul already fenced)
    __syncthreads();
    short* oY = pY; short* oZ = pZ; short* oW = s1;
    pY = s2; pZ = s0; s0 = oY; s1 = oZ; s2 = oW;
  }
  mm64(s0, pZ, pY, tid);  // P = Z @ Y
  __syncthreads();
#pragma unroll
  for (int e = 0; e < 16; e++) {  // s0 = 3I - P (in place, own elements only)
    int idx = tid + 256 * e;
    int r = idx >> 6, c = idx & 63;
    float p = bf2f(s0[idx]);
    s0[idx] = f2bf((r == c ? 3.0f : 0.0f) - p);
  }
  if (tid < 64) scol[tid] = 0.0f;
  __syncthreads();
  mmcolsum(pY, s0, scol, tid);  // column sums of R = Y @ (3I - P)
  __syncthreads();
  if (tid < 8) {
    float sc = 0.5f * sqrtf(normA) * (1.0f / 64.0f);
    float acc2 = pb1[tid];
    for (int c = 0; c < 64; c++) acc2 += scol[c] * sc * w1[tid * 64 + c];
    hbuf[tid] = fmaxf(acc2, 0.0f);
  }
  __syncthreads();
  if (tid < 64) {
    float acc2 = pb2[tid];
#pragma unroll
    for (int j = 0; j < 8; j++) acc2 += hbuf[j] * w2[tid * 8 + j];
    float g = 1.0f / (1.0f + __expf(-acc2));
    gate_sh[tid] = g;
    wt_store(gatews + b * 64 + tid, g);
  }
}

// gate multiply of this block's own chunk: 64 rows x W4 float4s, L2-warm.
template <int W4>
__device__ __forceinline__ void gate_phase(const float* __restrict__ x,
                                           float* __restrict__ out, int b,
                                           int m0, int tid,
                                           const float* gate_sh) {
  const float4* xp = (const float4*)x;
  float4* op = (float4*)out;
  size_t base = (size_t)b * CC * (MM / 4) + (m0 >> 2);
#pragma unroll
  for (int k = 0; k < (64 * W4) / 256; k++) {
    int i = tid + 256 * k;
    int c = i / W4;
    int off = i - c * W4;
    float g = gate_sh[c];
    size_t idx = base + (size_t)c * (MM / 4) + off;
    float4 v = xp[idx];
    v.x *= g; v.y *= g; v.z *= g; v.w *= g;
    op[idx] = v;
  }
}

// ---------------- the single fused kernel ----------------
__global__ __launch_bounds__(256, 2) void fused_k(
    const float* __restrict__ x, float* __restrict__ pg, float* __restrict__ ps,
    int* __restrict__ ctr, int* __restrict__ flag, const float* __restrict__ w1,
    const float* __restrict__ pb1, const float* __restrict__ w2,
    const float* __restrict__ pb2, float* __restrict__ gatews,
    float* __restrict__ out) {
  __shared__ __align__(16) unsigned char smem[65536];
  float(*red)[4096] = reinterpret_cast<float(*)[4096]>(smem);

  int b = blockIdx.x / NCHUNKS;
  int chunk = blockIdx.x % NCHUNKS;
  int tid = threadIdx.x;
  int w = tid >> 6, lane = tid & 63;
  int quad = lane >> 4, col = lane & 15;
  const float* xb = x + (size_t)b * CC * MM;

  f32x4 acc[4][4];
#pragma unroll
  for (int i = 0; i < 4; i++)
#pragma unroll
    for (int j = 0; j < 4; j++) acc[i][j] = (f32x4){0.f, 0.f, 0.f, 0.f};
  float csum[4] = {0.f, 0.f, 0.f, 0.f};

  // chunks 0-7: 5 steps (640 m), chunks 8-15: 4 steps (512 m)
  int m0;
  if (chunk < 8) {
    m0 = chunk * 640;
    gram_body<5>(xb, m0 + w * 160, quad, col, acc, csum);
  } else {
    m0 = 5120 + (chunk - 8) * 512;
    gram_body<4>(xb, m0 + w * 128, quad, col, acc, csum);
  }

  // per-wave channel sums -> write-through
#pragma unroll
  for (int rb = 0; rb < 4; rb++) {
    float c0 = csum[rb];
    c0 += __shfl_xor(c0, 16);
    c0 += __shfl_xor(c0, 32);
    if (lane < 16)
      wt_store(ps + (size_t)blockIdx.x * 256 + w * 64 + rb * 16 + lane, c0);
  }

  // block-level reduce of the 4 waves' partial Grams -> write-through
#pragma unroll
  for (int i = 0; i < 4; i++)
#pragma unroll
    for (int j = 0; j < 4; j++)
#pragma unroll
      for (int r = 0; r < 4; r++)
        red[w][(i * 16 + quad * 4 + r) * 64 + j * 16 + col] = acc[i][j][r];
  __syncthreads();
  float* covb = pg + (size_t)blockIdx.x * 4096;
#pragma unroll
  for (int e = 0; e < 16; e++) {
    int idx = tid + 256 * e;
    float v = (red[0][idx] + red[1][idx]) + (red[2][idx] + red[3][idx]);
    wt_store(covb + idx, v);
  }

  // -------- fence-free last-arrival election --------
  // __syncthreads drains vmcnt -> this block's write-through stores are at
  // the coherence point before the counter increment.
  __syncthreads();
  volatile int* pold = (int*)smem;  // overlays red; red is dead now
  if (tid == 0)
    *pold = __hip_atomic_fetch_add(ctr + b, 1, __ATOMIC_RELAXED,
                                   __HIP_MEMORY_SCOPE_AGENT);
  __syncthreads();
  int oldv = *pold;
  __syncthreads();  // everyone has oldv before smem is reused by ns_tail

  float* gate_sh = (float*)(smem + GATE_SH_OFF);
  if (oldv == NCHUNKS - 1) {
    // winner: all 16 partials are at the coherence point
    ns_tail(smem, b, tid, pg, ps, w1, pb1, w2, pb2, gatews);
    __syncthreads();  // gate_sh ready; gatews write-through drained (all thr)
    if (tid == 0)
      __hip_atomic_store(flag + b, 1, __ATOMIC_RELAXED,
                         __HIP_MEMORY_SCOPE_AGENT);
  } else {
    // waiter: spin on tid0 only, with backoff. Deadlock-free: full residency
    // (512 blocks = 2/CU capacity) + in-order dispatch.
    if (tid == 0) {
      while (__hip_atomic_load(flag + b, __ATOMIC_RELAXED,
                               __HIP_MEMORY_SCOPE_AGENT) == 0)
        __builtin_amdgcn_s_sleep(8);
    }
    __syncthreads();
    if (tid < 64) gate_sh[tid] = ag_load(gatews + b * 64 + tid);
    __syncthreads();
  }

  // -------- gate phase: own chunk, x is L2-warm from the gram read --------
  if (chunk < 8)
    gate_phase<160>(x, out, b, m0, tid, gate_sh);
  else
    gate_phase<128>(x, out, b, m0, tid, gate_sh);
}

// ================= fallback: 3-kernel plain-store path =============
__global__ __launch_bounds__(256, 2) void gram_k_leg(const float* __restrict__ x,
                                                     float* __restrict__ pg,
                                                     float* __restrict__ ps) {
  int b = blockIdx.x / NCHUNKS;
  int chunk = blockIdx.x % NCHUNKS;
  int tid = threadIdx.x;
  int w = tid >> 6, lane = tid & 63;
  int quad = lane >> 4, col = lane & 15;
  const float* xb = x + (size_t)b * CC * MM;

  f32x4 acc[4][4];
#pragma unroll
  for (int i = 0; i < 4; i++)
#pragma unroll
    for (int j = 0; j < 4; j++) acc[i][j] = (f32x4){0.f, 0.f, 0.f, 0.f};
  float csum[4] = {0.f, 0.f, 0.f, 0.f};
  if (chunk < 8) {
    gram_body<5>(xb, chunk * 640 + w * 160, quad, col, acc, csum);
  } else {
    gram_body<4>(xb, 5120 + (chunk - 8) * 512 + w * 128, quad, col, acc, csum);
  }
#pragma unroll
  for (int rb = 0; rb < 4; rb++) {
    float c0 = csum[rb];
    c0 += __shfl_xor(c0, 16);
    c0 += __shfl_xor(c0, 32);
    if (lane < 16)
      ps[(size_t)blockIdx.x * 256 + w * 64 + rb * 16 + lane] = c0;
  }
  __shared__ float red[4][4096];
#pragma unroll
  for (int i = 0; i < 4; i++)
#pragma unroll
    for (int j = 0; j < 4; j++)
#pragma unroll
      for (int r = 0; r < 4; r++)
        red[w][(i * 16 + quad * 4 + r) * 64 + j * 16 + col] = acc[i][j][r];
  __syncthreads();
  float* covb = pg + (size_t)blockIdx.x * 4096;
#pragma unroll
  for (int e = 0; e < 16; e++) {
    int idx = tid + 256 * e;
    covb[idx] = (red[0][idx] + red[1][idx]) + (red[2][idx] + red[3][idx]);
  }
}

__global__ __launch_bounds__(256) void ns_k_leg(const float* __restrict__ pg,
                                                const float* __restrict__ ps,
                                                const float* __restrict__ w1,
                                                const float* __restrict__ pb1,
                                                const float* __restrict__ w2,
                                                const float* __restrict__ pb2,
                                                float* __restrict__ gatews) {
  __shared__ __align__(16) unsigned char smem[60416];
  ns_tail(smem, blockIdx.x, threadIdx.x, pg, ps, w1, pb1, w2, pb2, gatews);
}

__global__ __launch_bounds__(256) void gate_mul_leg(const float* __restrict__ x,
                                                    const float* __restrict__ gatews,
                                                    float* __restrict__ out) {
  int bc = blockIdx.x;
  float g = gatews[bc];
  const float4* xp = (const float4*)(x + (size_t)bc * MM);
  float4* op = (float4*)(out + (size_t)bc * MM);
  int t = threadIdx.x;
#pragma unroll
  for (int it = 0; it < 9; ++it) {
    float4 v = xp[t + it * 256];
    v.x *= g; v.y *= g; v.z *= g; v.w *= g;
    op[t + it * 256] = v;
  }
}

extern "C" void kernel_launch(void* const* d_in, const int* in_sizes, int n_in,
                              void* d_out, int out_size, void* d_ws, size_t ws_size,
                              hipStream_t stream) {
  const float* x = (const float*)d_in[0];
  const float* w1 = (const float*)d_in[1];
  const float* b1 = (const float*)d_in[2];
  const float* w2 = (const float*)d_in[3];
  const float* b2 = (const float*)d_in[4];
  float* out = (float*)d_out;
  float* ws = (float*)d_ws;

  const size_t NPG = (size_t)BB * NCHUNKS * 4096;  // 2M floats = 8 MB
  const size_t NPS = (size_t)BB * NCHUNKS * 256;   // 128K floats = 512 KB
  float* pg = ws;
  float* psum = ws + NPG;
  float* gatews = psum + NPS;          // 2048 fp32, rewritten every call
  int* ctr = (int*)(gatews + BB * CC); // 32 ints
  int* flag = ctr + BB;                // 32 ints
  const size_t needP = (NPG + NPS + BB * CC + 2 * BB) * sizeof(float);

  if (ws_size >= needP) {
    hipMemsetAsync(ctr, 0, 2 * BB * sizeof(int), stream);  // 256 B, mandatory
    fused_k<<<BB * NCHUNKS, 256, 0, stream>>>(x, pg, psum, ctr, flag, w1, b1,
                                              w2, b2, gatews, out);
  } else {
    // 3-kernel fallback (no election, no spin)
    gram_k_leg<<<BB * NCHUNKS, 256, 0, stream>>>(x, pg, psum);
    ns_k_leg<<<BB, 256, 0, stream>>>(pg, psum, w1, b1, w2, b2, gatews);
    gate_mul_leg<<<BB * CC, 256, 0, stream>>>(x, gatews, out);
  }
}

// Round 10
// 168.375 us; speedup vs baseline: 1.5624x; 1.0053x over previous
//
#include <hip/hip_runtime.h>
#include <math.h>

// SecondOrderChannelAttension on MI355X (gfx950)
// B=32, C=64, H=W=96 -> M=9216, RED=8
//
// TWO dispatches:
//   memset  : zero 32 election counters + 32 gate-ready flags (256 B).
//             Mandatory every call (d_ws is poisoned between graph replays).
//   fused_k (512 blocks, 3/CU via 42KB LDS + launch_bounds(256,3)):
//     gram -> fence-free publication -> last-arrival election -> winner runs
//     NS + gate MLP -> waiters spin on flag -> every block gates its own
//     x-chunk (L3-warm; r9 FETCH proved x is read from HBM only once).
//
// r9 diagnosis: VGPR_Count=104 < the 128+ needed for the gram prefetch
// pipeline (acc 64 + cur 32 + nxt 32) => compiler serialized the 8 prefetch
// loads => ~900ns exposed latency per load => gram ~40us vs 13us roofline.
// Fixes this round: sched_barrier(0) pins loads-before-compute (forces nxt
// live), LDS 64->42KB + launch_bounds(256,3) lifts occupancy 2->3 blocks/CU.
//
// NOTE: hipLaunchCooperativeKernel is NOT graph-capturable here (round 4).
// NOTE: __threadfence()/release fences in wide kernels cost ~100us (r2,r5);
//       publication uses agent-scope relaxed atomic (write-through) stores,
//       never dirties L2, no wbl2. Winner gathers via agent atomic loads
//       (coherence point) -- no acquire fence, caches stay warm.
// NOTE: d_ws is POISONED between replays; d_out is NOT re-zeroed (round 6).
// NOTE: spin safety: grid 512 <= residency capacity 768 (3 blocks/CU x 256).

#define BB 32
#define CC 64
#define MM 9216
#define NCHUNKS 16

// LDS layout (42 KB total):
//   gram phase: red[2][4096] @ 0..32768 (2-stage wave reduce)
//   ns phase:   nb0@0 nb1@8192 nb2@16384 nb3@24576 nb4@32768 (5x8KB)
//               gsum@16384 (16KB, overlays nb2+nb3; dead before mm64->nb2)
//               mu@40960 scol@41216 hbuf@41472 pnorm@41504
//   gate_sh @ 41536 (256B), pold @ 41856
#define SMEM_BYTES 43008
#define GATE_SH_OFF 41536
#define POLD_OFF 41856

typedef __attribute__((ext_vector_type(8))) short bf16x8;
typedef __attribute__((ext_vector_type(4))) float f32x4;

__device__ __forceinline__ short f2bf(float f) {
  unsigned u = __builtin_bit_cast(unsigned, f);
  return (short)(unsigned short)((u + 0x8000u) >> 16);  // round-half-up, fine here
}
__device__ __forceinline__ float bf2f(short h) {
  unsigned u = ((unsigned)(unsigned short)h) << 16;
  return __builtin_bit_cast(float, u);
}
// write-through (agent-scope) store: visible at coherence point once vmcnt
// drains; no dirty L2 line anywhere.
__device__ __forceinline__ void wt_store(float* p, float v) {
  __hip_atomic_store(p, v, __ATOMIC_RELAXED, __HIP_MEMORY_SCOPE_AGENT);
}
// agent-scope relaxed atomic loads: read the coherence point (correct without
// any fence; do NOT invalidate local caches).
__device__ __forceinline__ float ag_load(const float* p) {
  return __hip_atomic_load(p, __ATOMIC_RELAXED, __HIP_MEMORY_SCOPE_AGENT);
}
__device__ __forceinline__ float2 ag_load2(const float* p) {
  unsigned long long u = __hip_atomic_load((const unsigned long long*)p,
                                           __ATOMIC_RELAXED,
                                           __HIP_MEMORY_SCOPE_AGENT);
  return __builtin_bit_cast(float2, u);
}

// ---------------- gram inner loop ----------------
// Fragment trick: for Gram, the B-operand fragment (B[k][n] = X[n][k]) has the
// same lane mapping as the A fragment of X rows -> load once, use twice.
template <int NSTEP>
__device__ __forceinline__ void gram_body(const float* __restrict__ xb, int mwave,
                                          int quad, int col,
                                          f32x4 acc[4][4], float csum[4]) {
  const float* base[4];
#pragma unroll
  for (int rb = 0; rb < 4; rb++)
    base[rb] = xb + (size_t)(rb * 16 + col) * MM + mwave + quad * 8;

  float4 cur[4][2];
#pragma unroll
  for (int rb = 0; rb < 4; rb++) {
    cur[rb][0] = *(const float4*)(base[rb]);
    cur[rb][1] = *(const float4*)(base[rb] + 4);
  }
#pragma unroll
  for (int s = 0; s < NSTEP; s++) {
    float4 nxt[4][2];
    if (s + 1 < NSTEP) {
#pragma unroll
      for (int rb = 0; rb < 4; rb++) {
        const float* p = base[rb] + (s + 1) * 32;
        nxt[rb][0] = *(const float4*)(p);
        nxt[rb][1] = *(const float4*)(p + 4);
      }
    }
    // Pin: all 8 prefetch loads issued ABOVE this point; compute below may
    // not hoist past it, loads may not sink. Forces nxt[] live across the
    // step's compute -> the software pipeline actually materializes
    // (r9: VGPR=104 proved the compiler serialized it otherwise).
    __builtin_amdgcn_sched_barrier(0);
    bf16x8 frag[4];
#pragma unroll
    for (int rb = 0; rb < 4; rb++) {
      float v0 = cur[rb][0].x, v1 = cur[rb][0].y, v2 = cur[rb][0].z, v3 = cur[rb][0].w;
      float v4 = cur[rb][1].x, v5 = cur[rb][1].y, v6 = cur[rb][1].z, v7 = cur[rb][1].w;
      csum[rb] += ((v0 + v1) + (v2 + v3)) + ((v4 + v5) + (v6 + v7));
      bf16x8 f;
      f[0] = f2bf(v0); f[1] = f2bf(v1); f[2] = f2bf(v2); f[3] = f2bf(v3);
      f[4] = f2bf(v4); f[5] = f2bf(v5); f[6] = f2bf(v6); f[7] = f2bf(v7);
      frag[rb] = f;
    }
#pragma unroll
    for (int i = 0; i < 4; i++)
#pragma unroll
      for (int j = 0; j < 4; j++)
        acc[i][j] = __builtin_amdgcn_mfma_f32_16x16x32_bf16(frag[i], frag[j],
                                                            acc[i][j], 0, 0, 0);
    if (s + 1 < NSTEP) {
#pragma unroll
      for (int rb = 0; rb < 4; rb++) {
        cur[rb][0] = nxt[rb][0];
        cur[rb][1] = nxt[rb][1];
      }
    }
  }
}

// ---------------- 64x64 NS matmuls (LDS, bf16 MFMA) ----------------
// All NS iterates are symmetric (polynomials in A), so row-major read serves
// as the k-major B fragment.
__device__ __forceinline__ void mm64(short* __restrict__ D, const short* __restrict__ A,
                                     const short* __restrict__ Bm, int tid) {
  int w = tid >> 6, lane = tid & 63, quad = lane >> 4, col = lane & 15;
  f32x4 acc[4];
#pragma unroll
  for (int j = 0; j < 4; j++) acc[j] = (f32x4){0.f, 0.f, 0.f, 0.f};
#pragma unroll
  for (int ks = 0; ks < 2; ks++) {
    int k0 = ks * 32 + quad * 8;
    bf16x8 fa = *(const bf16x8*)(A + (w * 16 + col) * 64 + k0);
#pragma unroll
    for (int j = 0; j < 4; j++) {
      bf16x8 fb = *(const bf16x8*)(Bm + (j * 16 + col) * 64 + k0);
      acc[j] = __builtin_amdgcn_mfma_f32_16x16x32_bf16(fa, fb, acc[j], 0, 0, 0);
    }
  }
#pragma unroll
  for (int j = 0; j < 4; j++)
#pragma unroll
    for (int r = 0; r < 4; r++)
      D[(w * 16 + quad * 4 + r) * 64 + j * 16 + col] = f2bf(acc[j][r]);
}

__device__ __forceinline__ void mmcolsum(const short* __restrict__ A,
                                         const short* __restrict__ Bm,
                                         float* scol, int tid) {
  int w = tid >> 6, lane = tid & 63, quad = lane >> 4, col = lane & 15;
  f32x4 acc[4];
#pragma unroll
  for (int j = 0; j < 4; j++) acc[j] = (f32x4){0.f, 0.f, 0.f, 0.f};
#pragma unroll
  for (int ks = 0; ks < 2; ks++) {
    int k0 = ks * 32 + quad * 8;
    bf16x8 fa = *(const bf16x8*)(A + (w * 16 + col) * 64 + k0);
#pragma unroll
    for (int j = 0; j < 4; j++) {
      bf16x8 fb = *(const bf16x8*)(Bm + (j * 16 + col) * 64 + k0);
      acc[j] = __builtin_amdgcn_mfma_f32_16x16x32_bf16(fa, fb, acc[j], 0, 0, 0);
    }
  }
#pragma unroll
  for (int j = 0; j < 4; j++) {
    float t = (acc[j][0] + acc[j][1]) + (acc[j][2] + acc[j][3]);
    atomicAdd(&scol[j * 16 + col], t);  // LDS atomic: sums all 64 rows
  }
}

// NS + gate-MLP tail. Gathers partials with agent atomic loads (no fence
// needed, caches untouched). Fills gate_sh (LDS) AND gatews (write-through).
// gsum overlays nb2+nb3: it is fully consumed (into nb0/nb1 + normA) before
// mm64 first writes nb2.
__device__ __forceinline__ void ns_tail(unsigned char* smem, int b, int tid,
                                        const float* __restrict__ pg,
                                        const float* __restrict__ ps,
                                        const float* __restrict__ w1,
                                        const float* __restrict__ pb1,
                                        const float* __restrict__ w2,
                                        const float* __restrict__ pb2,
                                        float* __restrict__ gatews) {
  short* nb0 = (short*)smem;             // 5 x 8 KB bf16 64x64 buffers
  short* nb1 = nb0 + 4096;
  short* nb2 = nb0 + 8192;
  short* nb3 = nb0 + 12288;
  short* nb4 = nb0 + 16384;
  float* gsum = (float*)(smem + 16384);  // 16 KB, overlays nb2+nb3
  float* mu = (float*)(smem + 40960);
  float* scol = (float*)(smem + 41216);
  float* hbuf = (float*)(smem + 41472);
  float* pnorm = (float*)(smem + 41504);
  float* gate_sh = (float*)(smem + GATE_SH_OFF);

  {
    // gather: 8B agent atomic loads, independent -> pipelined
    const float* pgb = pg + (size_t)b * NCHUNKS * 4096;
#pragma unroll
    for (int e = 0; e < 8; e++) {
      int i2 = tid + 256 * e;  // float2 index, 0..2047
      float sx = 0.f, sy = 0.f;
#pragma unroll
      for (int c = 0; c < NCHUNKS; c++) {
        float2 v = ag_load2(pgb + c * 4096 + 2 * i2);
        sx += v.x; sy += v.y;
      }
      gsum[2 * i2] = sx;
      gsum[2 * i2 + 1] = sy;
    }
    if (tid < 64) {
      const float* psb = ps + (size_t)b * NCHUNKS * 256;
      float s = 0.f;
#pragma unroll
      for (int c = 0; c < NCHUNKS; c++)
#pragma unroll
        for (int sub = 0; sub < 4; sub++)
          s += ag_load(psb + c * 256 + sub * 64 + tid);
      mu[tid] = s * (1.0f / MM);
    }
  }
  __syncthreads();

  if (tid < 64) {
    float d = gsum[tid * 65] * (1.0f / MM) - mu[tid] * mu[tid];
#pragma unroll
    for (int off = 32; off >= 1; off >>= 1) d += __shfl_down(d, off);
    if (tid == 0) *pnorm = d;
  }
  __syncthreads();
  float normA = *pnorm;
  float rn = 1.0f / normA;
  // A -> nb0, Z = ZY0 = 1.5I - 0.5A -> nb1  (reads gsum; writes nb0/nb1 only)
#pragma unroll
  for (int e = 0; e < 16; e++) {
    int idx = tid + 256 * e;
    int r = idx >> 6, c = idx & 63;
    float cv = gsum[idx] * (1.0f / MM) - mu[r] * mu[c];
    float a = cv * rn;
    nb0[idx] = f2bf(a);
    nb1[idx] = f2bf((r == c ? 1.5f : 0.0f) - 0.5f * a);
  }
  __syncthreads();
  mm64(nb2, nb0, nb1, tid);  // Y = A @ ZY0   (first write to gsum region: ok, gsum dead)
  __syncthreads();
  short *pY = nb2, *pZ = nb1, *s0 = nb3, *s1 = nb4, *s2 = nb0;
  for (int it = 0; it < 3; ++it) {
    // T = 1.5I - 0.5 Z -> s0
#pragma unroll
    for (int e = 0; e < 16; e++) {
      int idx = tid + 256 * e;
      int r = idx >> 6, c = idx & 63;
      float z = bf2f(pZ[idx]);
      s0[idx] = f2bf((r == c ? 1.5f : 0.0f) - 0.5f * z);
    }
    __syncthreads();
    mm64(s1, s0, pY, tid);  // W = T @ Y
    __syncthreads();
    mm64(s2, pY, s1, tid);  // Ynew = Y @ W
    mm64(s0, s1, pZ, tid);  // Znew = W @ Z  (overwrites T; W-matmul already fenced)
    __syncthreads();
    short* oY = pY; short* oZ = pZ; short* oW = s1;
    pY = s2; pZ = s0; s0 = oY; s1 = oZ; s2 = oW;
  }
  mm64(s0, pZ, pY, tid);  // P = Z @ Y
  __syncthreads();
#pragma unroll
  for (int e = 0; e < 16; e++) {  // s0 = 3I - P (in place, own elements only)
    int idx = tid + 256 * e;
    int r = idx >> 6, c = idx & 63;
    float p = bf2f(s0[idx]);
    s0[idx] = f2bf((r == c ? 3.0f : 0.0f) - p);
  }
  if (tid < 64) scol[tid] = 0.0f;
  __syncthreads();
  mmcolsum(pY, s0, scol, tid);  // column sums of R = Y @ (3I - P)
  __syncthreads();
  if (tid < 8) {
    float sc = 0.5f * sqrtf(normA) * (1.0f / 64.0f);
    float acc2 = pb1[tid];
    for (int c = 0; c < 64; c++) acc2 += scol[c] * sc * w1[tid * 64 + c];
    hbuf[tid] = fmaxf(acc2, 0.0f);
  }
  __syncthreads();
  if (tid < 64) {
    float acc2 = pb2[tid];
#pragma unroll
    for (int j = 0; j < 8; j++) acc2 += hbuf[j] * w2[tid * 8 + j];
    float g = 1.0f / (1.0f + __expf(-acc2));
    gate_sh[tid] = g;
    wt_store(gatews + b * 64 + tid, g);
  }
}

// gate multiply of this block's own chunk: 64 rows x W4 float4s, L3-warm.
template <int W4>
__device__ __forceinline__ void gate_phase(const float* __restrict__ x,
                                           float* __restrict__ out, int b,
                                           int m0, int tid,
                                           const float* gate_sh) {
  const float4* xp = (const float4*)x;
  float4* op = (float4*)out;
  size_t base = (size_t)b * CC * (MM / 4) + (m0 >> 2);
#pragma unroll
  for (int k = 0; k < (64 * W4) / 256; k++) {
    int i = tid + 256 * k;
    int c = i / W4;
    int off = i - c * W4;
    float g = gate_sh[c];
    size_t idx = base + (size_t)c * (MM / 4) + off;
    float4 v = xp[idx];
    v.x *= g; v.y *= g; v.z *= g; v.w *= g;
    op[idx] = v;
  }
}

// ---------------- the single fused kernel ----------------
// 42 KB LDS -> 3 blocks/CU; launch_bounds(256,3) caps VGPR at ~170.
__global__ __launch_bounds__(256, 3) void fused_k(
    const float* __restrict__ x, float* __restrict__ pg, float* __restrict__ ps,
    int* __restrict__ ctr, int* __restrict__ flag, const float* __restrict__ w1,
    const float* __restrict__ pb1, const float* __restrict__ w2,
    const float* __restrict__ pb2, float* __restrict__ gatews,
    float* __restrict__ out) {
  __shared__ __align__(16) unsigned char smem[SMEM_BYTES];
  float(*red)[4096] = reinterpret_cast<float(*)[4096]>(smem);  // red[2][4096]

  int b = blockIdx.x / NCHUNKS;
  int chunk = blockIdx.x % NCHUNKS;
  int tid = threadIdx.x;
  int w = tid >> 6, lane = tid & 63;
  int quad = lane >> 4, col = lane & 15;
  const float* xb = x + (size_t)b * CC * MM;

  f32x4 acc[4][4];
#pragma unroll
  for (int i = 0; i < 4; i++)
#pragma unroll
    for (int j = 0; j < 4; j++) acc[i][j] = (f32x4){0.f, 0.f, 0.f, 0.f};
  float csum[4] = {0.f, 0.f, 0.f, 0.f};

  // chunks 0-7: 5 steps (640 m), chunks 8-15: 4 steps (512 m)
  int m0;
  if (chunk < 8) {
    m0 = chunk * 640;
    gram_body<5>(xb, m0 + w * 160, quad, col, acc, csum);
  } else {
    m0 = 5120 + (chunk - 8) * 512;
    gram_body<4>(xb, m0 + w * 128, quad, col, acc, csum);
  }

  // per-wave channel sums -> write-through
#pragma unroll
  for (int rb = 0; rb < 4; rb++) {
    float c0 = csum[rb];
    c0 += __shfl_xor(c0, 16);
    c0 += __shfl_xor(c0, 32);
    if (lane < 16)
      wt_store(ps + (size_t)blockIdx.x * 256 + w * 64 + rb * 16 + lane, c0);
  }

  // 2-stage wave reduce in red[2][4096] (32 KB): waves 0,1 write; waves 2,3
  // accumulate into the same element (disjoint lanes own disjoint idx).
  if (w < 2) {
#pragma unroll
    for (int i = 0; i < 4; i++)
#pragma unroll
      for (int j = 0; j < 4; j++)
#pragma unroll
        for (int r = 0; r < 4; r++)
          red[w][(i * 16 + quad * 4 + r) * 64 + j * 16 + col] = acc[i][j][r];
  }
  __syncthreads();
  if (w >= 2) {
#pragma unroll
    for (int i = 0; i < 4; i++)
#pragma unroll
      for (int j = 0; j < 4; j++)
#pragma unroll
        for (int r = 0; r < 4; r++)
          red[w - 2][(i * 16 + quad * 4 + r) * 64 + j * 16 + col] += acc[i][j][r];
  }
  __syncthreads();
  float* covb = pg + (size_t)blockIdx.x * 4096;
#pragma unroll
  for (int e = 0; e < 16; e++) {
    int idx = tid + 256 * e;
    wt_store(covb + idx, red[0][idx] + red[1][idx]);
  }

  // -------- fence-free last-arrival election --------
  // __syncthreads drains vmcnt -> this block's write-through stores are at
  // the coherence point before the counter increment.
  __syncthreads();
  volatile int* pold = (int*)(smem + POLD_OFF);
  if (tid == 0)
    *pold = __hip_atomic_fetch_add(ctr + b, 1, __ATOMIC_RELAXED,
                                   __HIP_MEMORY_SCOPE_AGENT);
  __syncthreads();
  int oldv = *pold;
  __syncthreads();  // everyone has oldv before smem is reused by ns_tail

  float* gate_sh = (float*)(smem + GATE_SH_OFF);
  if (oldv == NCHUNKS - 1) {
    // winner: all 16 partials are at the coherence point
    ns_tail(smem, b, tid, pg, ps, w1, pb1, w2, pb2, gatews);
    __syncthreads();  // gate_sh ready; gatews write-through drained (all thr)
    if (tid == 0)
      __hip_atomic_store(flag + b, 1, __ATOMIC_RELAXED,
                         __HIP_MEMORY_SCOPE_AGENT);
  } else {
    // waiter: spin on tid0 only, with backoff. Deadlock-free: grid 512 <=
    // capacity 768 (3 blocks/CU) -> all blocks resident.
    if (tid == 0) {
      while (__hip_atomic_load(flag + b, __ATOMIC_RELAXED,
                               __HIP_MEMORY_SCOPE_AGENT) == 0)
        __builtin_amdgcn_s_sleep(8);
    }
    __syncthreads();
    if (tid < 64) gate_sh[tid] = ag_load(gatews + b * 64 + tid);
    __syncthreads();
  }

  // -------- gate phase: own chunk, x is L3-warm from the gram read --------
  if (chunk < 8)
    gate_phase<160>(x, out, b, m0, tid, gate_sh);
  else
    gate_phase<128>(x, out, b, m0, tid, gate_sh);
}

// ================= fallback: 3-kernel plain-store path =============
__global__ __launch_bounds__(256, 2) void gram_k_leg(const float* __restrict__ x,
                                                     float* __restrict__ pg,
                                                     float* __restrict__ ps) {
  int b = blockIdx.x / NCHUNKS;
  int chunk = blockIdx.x % NCHUNKS;
  int tid = threadIdx.x;
  int w = tid >> 6, lane = tid & 63;
  int quad = lane >> 4, col = lane & 15;
  const float* xb = x + (size_t)b * CC * MM;

  f32x4 acc[4][4];
#pragma unroll
  for (int i = 0; i < 4; i++)
#pragma unroll
    for (int j = 0; j < 4; j++) acc[i][j] = (f32x4){0.f, 0.f, 0.f, 0.f};
  float csum[4] = {0.f, 0.f, 0.f, 0.f};
  if (chunk < 8) {
    gram_body<5>(xb, chunk * 640 + w * 160, quad, col, acc, csum);
  } else {
    gram_body<4>(xb, 5120 + (chunk - 8) * 512 + w * 128, quad, col, acc, csum);
  }
#pragma unroll
  for (int rb = 0; rb < 4; rb++) {
    float c0 = csum[rb];
    c0 += __shfl_xor(c0, 16);
    c0 += __shfl_xor(c0, 32);
    if (lane < 16)
      ps[(size_t)blockIdx.x * 256 + w * 64 + rb * 16 + lane] = c0;
  }
  __shared__ float red[2][4096];
  if (w < 2) {
#pragma unroll
    for (int i = 0; i < 4; i++)
#pragma unroll
      for (int j = 0; j < 4; j++)
#pragma unroll
        for (int r = 0; r < 4; r++)
          red[w][(i * 16 + quad * 4 + r) * 64 + j * 16 + col] = acc[i][j][r];
  }
  __syncthreads();
  if (w >= 2) {
#pragma unroll
    for (int i = 0; i < 4; i++)
#pragma unroll
      for (int j = 0; j < 4; j++)
#pragma unroll
        for (int r = 0; r < 4; r++)
          red[w - 2][(i * 16 + quad * 4 + r) * 64 + j * 16 + col] += acc[i][j][r];
  }
  __syncthreads();
  float* covb = pg + (size_t)blockIdx.x * 4096;
#pragma unroll
  for (int e = 0; e < 16; e++) {
    int idx = tid + 256 * e;
    covb[idx] = red[0][idx] + red[1][idx];
  }
}

__global__ __launch_bounds__(256) void ns_k_leg(const float* __restrict__ pg,
                                                const float* __restrict__ ps,
                                                const float* __restrict__ w1,
                                                const float* __restrict__ pb1,
                                                const float* __restrict__ w2,
                                                const float* __restrict__ pb2,
                                                float* __restrict__ gatews) {
  __shared__ __align__(16) unsigned char smem[SMEM_BYTES];
  ns_tail(smem, blockIdx.x, threadIdx.x, pg, ps, w1, pb1, w2, pb2, gatews);
}

__global__ __launch_bounds__(256) void gate_mul_leg(const float* __restrict__ x,
                                                    const float* __restrict__ gatews,
                                                    float* __restrict__ out) {
  int bc = blockIdx.x;
  float g = gatews[bc];
  const float4* xp = (const float4*)(x + (size_t)bc * MM);
  float4* op = (float4*)(out + (size_t)bc * MM);
  int t = threadIdx.x;
#pragma unroll
  for (int it = 0; it < 9; ++it) {
    float4 v = xp[t + it * 256];
    v.x *= g; v.y *= g; v.z *= g; v.w *= g;
    op[t + it * 256] = v;
  }
}

extern "C" void kernel_launch(void* const* d_in, const int* in_sizes, int n_in,
                              void* d_out, int out_size, void* d_ws, size_t ws_size,
                              hipStream_t stream) {
  const float* x = (const float*)d_in[0];
  const float* w1 = (const float*)d_in[1];
  const float* b1 = (const float*)d_in[2];
  const float* w2 = (const float*)d_in[3];
  const float* b2 = (const float*)d_in[4];
  float* out = (float*)d_out;
  float* ws = (float*)d_ws;

  const size_t NPG = (size_t)BB * NCHUNKS * 4096;  // 2M floats = 8 MB
  const size_t NPS = (size_t)BB * NCHUNKS * 256;   // 128K floats = 512 KB
  float* pg = ws;
  float* psum = ws + NPG;
  float* gatews = psum + NPS;          // 2048 fp32, rewritten every call
  int* ctr = (int*)(gatews + BB * CC); // 32 ints
  int* flag = ctr + BB;                // 32 ints
  const size_t needP = (NPG + NPS + BB * CC + 2 * BB) * sizeof(float);

  if (ws_size >= needP) {
    hipMemsetAsync(ctr, 0, 2 * BB * sizeof(int), stream);  // 256 B, mandatory
    fused_k<<<BB * NCHUNKS, 256, 0, stream>>>(x, pg, psum, ctr, flag, w1, b1,
                                              w2, b2, gatews, out);
  } else {
    // 3-kernel fallback (no election, no spin)
    gram_k_leg<<<BB * NCHUNKS, 256, 0, stream>>>(x, pg, psum);
    ns_k_leg<<<BB, 256, 0, stream>>>(pg, psum, w1, b1, w2, b2, gatews);
    gate_mul_leg<<<BB * CC, 256, 0, stream>>>(x, gatews, out);
  }
}